// Round 3
// baseline (600.342 us; speedup 1.0000x reference)
//
#include <hip/hip_runtime.h>
#include <cstdint>
#include <math.h>

typedef float f32x4 __attribute__((ext_vector_type(4)));

// Skinny GEMM, j-blocked: block (bx,by) computes, for rows [bx*16, bx*16+16) and
// j in [by*JB, by*JB+JB):   Ypart[row][k] = sum_j A[row][j] * MT[k][j]
// MT slice is staged to LDS ONCE per block (one barrier); the main loop's only
// vmcnt traffic is the A stream (LDS reads use lgkmcnt) -> in-order vmcnt
// retirement never couples m-consumes to in-flight HBM prefetches.
// EPI 0: direct write out[k*N + row]  (use when gridDim.y == 1, e.g. X@W1)
// EPI 3: write partials out[((by*K)+k)*N + row]
template<int K, int JB, int EPI>
__launch_bounds__(256, 2)
__global__ void skinny_gemm(const float* __restrict__ A, int lda,
                            const float* __restrict__ MT, int ldm,
                            float* __restrict__ out, int N)
{
    __shared__ float lds[K * JB];
    const int tid  = (int)threadIdx.x;
    const int lane = tid & 63;
    const int wave = tid >> 6;
    const int row0 = blockIdx.x * 16 + wave * 4;
    const int j0   = blockIdx.y * JB;

    // ---- stage MT[0:K][j0:j0+JB] into LDS (flat, k-major) ----
    constexpr int STAGE_ITERS = (K * JB) / (256 * 4);   // 4 floats (16B) per thread per iter
#pragma unroll
    for (int i = 0; i < STAGE_ITERS; ++i) {
        const int fbase = i * 1024 + wave * 256;        // wave-uniform float index
        const int k  = fbase / JB;                      // wave chunk never straddles rows (JB % 256 == 0)
        const int jj = fbase % JB;
        const float* g = MT + (size_t)k * ldm + j0 + jj + lane * 4;   // per-lane global
        __builtin_amdgcn_global_load_lds(
            (const __attribute__((address_space(1))) void*)g,
            (__attribute__((address_space(3))) void*)(lds + fbase),   // wave-uniform dest
            16, 0, 0);
    }
    __syncthreads();    // only barrier in the kernel

    // ---- main loop: stream A with 2-deep register prefetch ----
    float acc[4][K];
#pragma unroll
    for (int r = 0; r < 4; ++r)
#pragma unroll
        for (int k = 0; k < K; ++k) acc[r][k] = 0.f;

    const float* ap[4];
#pragma unroll
    for (int r = 0; r < 4; ++r)
        ap[r] = A + (size_t)(row0 + r) * lda + j0 + lane * 4;

    constexpr int JS = JB / 256;                        // j-steps of 256 cols (64 lanes x f32x4)
    f32x4 abuf[2][4];
#pragma unroll
    for (int r = 0; r < 4; ++r)
        abuf[0][r] = __builtin_nontemporal_load((const f32x4*)(ap[r]));
    if (JS > 1) {
#pragma unroll
        for (int r = 0; r < 4; ++r)
            abuf[1][r] = __builtin_nontemporal_load((const f32x4*)(ap[r] + 256));
    }

#pragma unroll
    for (int js = 0; js < JS; ++js) {
        const int cur = js & 1;
        f32x4 a[4];
#pragma unroll
        for (int r = 0; r < 4; ++r) a[r] = abuf[cur][r];
        if (js + 2 < JS) {
#pragma unroll
            for (int r = 0; r < 4; ++r)
                abuf[cur][r] = __builtin_nontemporal_load((const f32x4*)(ap[r] + (size_t)(js + 2) * 256));
        }
        const float* mrow = lds + js * 256 + lane * 4;
#pragma unroll
        for (int k = 0; k < K; ++k) {
            const f32x4 m = *(const f32x4*)(mrow + k * JB);   // ds_read_b128, lgkmcnt only
#pragma unroll
            for (int r = 0; r < 4; ++r)
                acc[r][k] += a[r].x * m.x + a[r].y * m.y + a[r].z * m.z + a[r].w * m.w;
        }
    }

    // ---- 64-lane butterfly reduce ----
#pragma unroll
    for (int s = 1; s < 64; s <<= 1)
#pragma unroll
        for (int r = 0; r < 4; ++r)
#pragma unroll
            for (int k = 0; k < K; ++k)
                acc[r][k] += __shfl_xor(acc[r][k], s, 64);

    if (lane < K) {
#pragma unroll
        for (int r = 0; r < 4; ++r) {
            float v = acc[r][0];
#pragma unroll
            for (int k = 1; k < K; ++k) if (lane == k) v = acc[r][k];
            if (EPI == 0)
                out[(size_t)lane * N + row0 + r] = v;
            else
                out[((size_t)blockIdx.y * K + lane) * N + row0 + r] = v;
        }
    }
}

__global__ void transpose_w1(const float* __restrict__ W1, float* __restrict__ W1T)
{
    const int i = blockIdx.x * 256 + threadIdx.x;   // 4096 elements
    const int k = i >> 8, c = i & 255;
    W1T[i] = W1[c * 16 + k];
}

// PT[k2][row] = sum_k relu(b1[k] + sum_jb part1[jb][k][row]) * W2[k][k2]
__global__ void reduce_epi1(const float* __restrict__ part1,   // [8][16][N]
                            const float* __restrict__ b1,
                            const float* __restrict__ W2,      // [16][8]
                            float* __restrict__ PT, int N)
{
    const int row = blockIdx.x * 256 + threadIdx.x;
    float h[16];
#pragma unroll
    for (int k = 0; k < 16; ++k) {
        float s = b1[k];
#pragma unroll
        for (int jb = 0; jb < 8; ++jb)
            s += part1[((size_t)jb * 16 + k) * N + row];
        h[k] = s > 0.f ? s : 0.f;
    }
#pragma unroll
    for (int k2 = 0; k2 < 8; ++k2) {
        float p = 0.f;
#pragma unroll
        for (int k = 0; k < 16; ++k) p += h[k] * W2[k * 8 + k2];
        PT[(size_t)k2 * N + row] = p;
    }
}

// z = relu(b2 + sum_jb part2), then decision-tree + pi epilogue, fused per row.
__global__ void reduce_epi2_tree(const float* __restrict__ part2,  // [8][8][N]
                                 const float* __restrict__ b2,
                                 const float* __restrict__ Wd,     // [8][16]
                                 const float* __restrict__ bd,     // [16]
                                 const float* __restrict__ mask,   // [16][16]
                                 const float* __restrict__ Wdec,   // [16][16]
                                 const float* __restrict__ bdec,   // [16]
                                 const float* __restrict__ pi,     // [16][10]
                                 float* __restrict__ out, int N)   // [N][10]
{
    const int row = blockIdx.x * 256 + threadIdx.x;
    float zv[8];
#pragma unroll
    for (int k = 0; k < 8; ++k) {
        float s = b2[k];
#pragma unroll
        for (int jb = 0; jb < 8; ++jb)
            s += part2[((size_t)jb * 8 + k) * N + row];
        zv[k] = s > 0.f ? s : 0.f;
    }
    float feat[16];
#pragma unroll
    for (int f = 0; f < 16; ++f) {
        float s = bd[f];
#pragma unroll
        for (int k = 0; k < 8; ++k) s += zv[k] * Wd[k * 16 + f];
        feat[f] = s > 0.f ? s : 0.f;
    }
    float fm[16];
#pragma unroll
    for (int f = 0; f < 16; ++f) {
        float s = 0.f;
#pragma unroll
        for (int g = 0; g < 16; ++g) s += feat[g] * mask[g * 16 + f];
        fm[f] = s;
    }
    float mu[16];
#pragma unroll
    for (int j = 0; j < 8; ++j) {
        const int f = 8 + j;
        float s = bdec[f];
#pragma unroll
        for (int g = 0; g < 16; ++g) s += fm[g] * Wdec[g * 16 + f];
        const float d = 1.f / (1.f + expf(-s));
        mu[2 * j]     = fm[f] * d;
        mu[2 * j + 1] = fm[f] * (1.f - d);
    }
#pragma unroll
    for (int c = 0; c < 10; ++c) {
        float s = 0.f;
#pragma unroll
        for (int m = 0; m < 16; ++m) {
            float p = pi[m * 10 + c];
            p = p > 0.f ? p : 0.f;
            s += mu[m] * p;
        }
        out[(size_t)row * 10 + c] = s;
    }
}

extern "C" void kernel_launch(void* const* d_in, const int* in_sizes, int n_in,
                              void* d_out, int out_size, void* d_ws, size_t ws_size,
                              hipStream_t stream)
{
    const float* X    = (const float*)d_in[0];   // [8192][256]
    const float* A    = (const float*)d_in[1];   // [8192][8192]
    const float* W1   = (const float*)d_in[2];   // [256][16]
    const float* b1   = (const float*)d_in[3];   // [16]
    const float* W2   = (const float*)d_in[4];   // [16][8]
    const float* b2   = (const float*)d_in[5];   // [8]
    const float* Wd   = (const float*)d_in[6];   // [8][16]
    const float* bd   = (const float*)d_in[7];   // [16]
    const float* mask = (const float*)d_in[8];   // [16][16]
    const float* Wdec = (const float*)d_in[9];   // [16][16]
    const float* bdec = (const float*)d_in[10];  // [16]
    const float* pi   = (const float*)d_in[11];  // [16][10]
    float* out = (float*)d_out;

    const int N = 8192;
    char* ws = (char*)d_ws;
    float* W1T   = (float*)ws;                             ws += 16 * 1024;       // 16x256
    float* M1T   = (float*)ws;                             ws += 512 * 1024;      // 16xN
    float* PT    = (float*)ws;                             ws += 256 * 1024;      // 8xN
    float* part1 = (float*)ws;                             ws += 8 * 16 * N * 4;  // 4 MB
    float* part2 = (float*)ws;                             /* 8 * 8 * N * 4 = 2 MB */

    // W1T[k][c] = W1[c][k]
    hipLaunchKernelGGL(transpose_w1, dim3(16), dim3(256), 0, stream, W1, W1T);
    // M1T = (X @ W1)^T        [16][N]   (single j-block: direct write)
    hipLaunchKernelGGL((skinny_gemm<16, 256, 0>), dim3(N / 16, 1), dim3(256), 0, stream,
                       X, 256, W1T, 256, M1T, N);
    // part1[jb][k][row] = partial of A @ M1  (K=16, 8 j-blocks of 1024)
    hipLaunchKernelGGL((skinny_gemm<16, 1024, 3>), dim3(N / 16, 8), dim3(256), 0, stream,
                       A, N, M1T, N, part1, N);
    // PT = (relu(sum + b1) @ W2)^T   [8][N]
    hipLaunchKernelGGL(reduce_epi1, dim3(N / 256), dim3(256), 0, stream, part1, b1, W2, PT, N);
    // part2[jb][k][row] = partial of A @ P  (K=8, 8 j-blocks of 1024)
    hipLaunchKernelGGL((skinny_gemm<8, 1024, 3>), dim3(N / 16, 8), dim3(256), 0, stream,
                       A, N, PT, N, part2, N);
    // z = relu(sum + b2) fused with tree + pi
    hipLaunchKernelGGL(reduce_epi2_tree, dim3(N / 256), dim3(256), 0, stream,
                       part2, b2, Wd, bd, mask, Wdec, bdec, pi, out, N);
}